// Round 1
// baseline (226.133 us; speedup 1.0000x reference)
//
#include <hip/hip_runtime.h>
#include <math.h>

// acc layout in d_ws (floats):
// [0]=sdf_sum  [1]=eik_sum(M+N)  [2]=morse_sum  [3]=h_sum  [4]=neigh_sum  [5]=inter_sum
static constexpr int BLOCK = 256;
static constexpr int WAVES = BLOCK / 64;
static constexpr int KVAL = 4;

__device__ __forceinline__ void norm3(float x, float y, float z,
                                      float& ox, float& oy, float& oz) {
  float inv = 1.0f / (sqrtf(x * x + y * y + z * z) + 1e-12f);
  ox = x * inv; oy = y * inv; oz = z * inv;
}

// va = normalize(u*cos+v*sin), vb = normalize(-u*sin+v*cos) for vertex n
__device__ __forceinline__ void crossfield(const float* __restrict__ u,
                                           const float* __restrict__ v,
                                           const float* __restrict__ theta,
                                           int n, float va[3], float vb[3]) {
  float s, c;
  __sincosf(theta[n], &s, &c);
  float ux = u[3 * n], uy = u[3 * n + 1], uz = u[3 * n + 2];
  float vx = v[3 * n], vy = v[3 * n + 1], vz = v[3 * n + 2];
  norm3(ux * c + vx * s, uy * c + vy * s, uz * c + vz * s, va[0], va[1], va[2]);
  norm3(vx * c - ux * s, vy * c - uy * s, vz * c - uz * s, vb[0], vb[1], vb[2]);
}

template <int NV>
__device__ __forceinline__ void block_accum(float (&p)[NV], float* __restrict__ acc,
                                            const int (&slot)[NV]) {
#pragma unroll
  for (int off = 32; off > 0; off >>= 1)
#pragma unroll
    for (int q = 0; q < NV; ++q) p[q] += __shfl_down(p[q], off, 64);
  __shared__ float sm[WAVES][NV];
  int wave = threadIdx.x >> 6, lane = threadIdx.x & 63;
  if (lane == 0)
#pragma unroll
    for (int q = 0; q < NV; ++q) sm[wave][q] = p[q];
  __syncthreads();
  if (threadIdx.x == 0) {
#pragma unroll
    for (int q = 0; q < NV; ++q) {
      float t = 0.f;
#pragma unroll
      for (int w = 0; w < WAVES; ++w) t += sm[w][q];
      atomicAdd(&acc[slot[q]], t);
    }
  }
}

__global__ __launch_bounds__(BLOCK) void vertex_kernel(
    const float* __restrict__ mp,     // [N]
    const float* __restrict__ grad,   // [N,3]
    const float* __restrict__ H,      // [N,9]
    const float* __restrict__ ngt,    // [N,3]
    const float* __restrict__ theta,  // [N]
    const float* __restrict__ u,      // [N,3]
    const float* __restrict__ v,      // [N,3]
    const float* __restrict__ rot,    // [N,K,9]
    const int* __restrict__ nbr,      // [N,K]
    float* __restrict__ acc, int N) {
  int n = blockIdx.x * blockDim.x + threadIdx.x;
  float p[5] = {0.f, 0.f, 0.f, 0.f, 0.f};
  if (n < N) {
    // sdf
    p[0] = fabsf(mp[n]);
    // eikonal (manifold part)
    float gx = grad[3 * n], gy = grad[3 * n + 1], gz = grad[3 * n + 2];
    p[1] = fabsf(sqrtf(gx * gx + gy * gy + gz * gz) - 1.0f);
    // hessian
    float h[9];
#pragma unroll
    for (int i = 0; i < 9; ++i) h[i] = H[9 * (size_t)n + i];
    // morse: sum_e |sum_d ngt[d]*H[d,e]|
    float n0 = ngt[3 * n], n1 = ngt[3 * n + 1], n2 = ngt[3 * n + 2];
    p[2] = fabsf(n0 * h[0] + n1 * h[3] + n2 * h[6]) +
           fabsf(n0 * h[1] + n1 * h[4] + n2 * h[7]) +
           fabsf(n0 * h[2] + n1 * h[5] + n2 * h[8]);
    // cross field at self
    float va[3], vb[3];
    crossfield(u, v, theta, n, va, vb);
    // vaH[e] = sum_d va[d]*H[d,e]; cross(vaH, va); abs-sum. Same for vb.
    {
      float a0 = va[0] * h[0] + va[1] * h[3] + va[2] * h[6];
      float a1 = va[0] * h[1] + va[1] * h[4] + va[2] * h[7];
      float a2 = va[0] * h[2] + va[1] * h[5] + va[2] * h[8];
      float b0 = vb[0] * h[0] + vb[1] * h[3] + vb[2] * h[6];
      float b1 = vb[0] * h[1] + vb[1] * h[4] + vb[2] * h[7];
      float b2 = vb[0] * h[2] + vb[1] * h[5] + vb[2] * h[8];
      p[3] = fabsf(a1 * va[2] - a2 * va[1]) + fabsf(a2 * va[0] - a0 * va[2]) +
             fabsf(a0 * va[1] - a1 * va[0]) + fabsf(b1 * vb[2] - b2 * vb[1]) +
             fabsf(b2 * vb[0] - b0 * vb[2]) + fabsf(b0 * vb[1] - b1 * vb[0]);
    }
    // neighbor consistency
    float nsum = 0.f;
    const float* R = rot + (size_t)n * (KVAL * 9);
#pragma unroll
    for (int k = 0; k < KVAL; ++k) {
      int j = nbr[KVAL * (size_t)n + k];
      float vaj[3], vbj[3];
      crossfield(u, v, theta, j, vaj, vbj);
      float r0 = R[9 * k + 0], r1 = R[9 * k + 1], r2 = R[9 * k + 2];
      float r3 = R[9 * k + 3], r4 = R[9 * k + 4], r5 = R[9 * k + 5];
      float r6 = R[9 * k + 6], r7 = R[9 * k + 7], r8 = R[9 * k + 8];
      float wa0 = r0 * vaj[0] + r1 * vaj[1] + r2 * vaj[2];
      float wa1 = r3 * vaj[0] + r4 * vaj[1] + r5 * vaj[2];
      float wa2 = r6 * vaj[0] + r7 * vaj[1] + r8 * vaj[2];
      float wb0 = r0 * vbj[0] + r1 * vbj[1] + r2 * vbj[2];
      float wb1 = r3 * vbj[0] + r4 * vbj[1] + r5 * vbj[2];
      float wb2 = r6 * vbj[0] + r7 * vbj[1] + r8 * vbj[2];
      float aa = fabsf(va[0] * wa0 + va[1] * wa1 + va[2] * wa2);
      float ab = fabsf(va[0] * wb0 + va[1] * wb1 + va[2] * wb2);
      float ba = fabsf(vb[0] * wa0 + vb[1] * wa1 + vb[2] * wa2);
      float bb = fabsf(vb[0] * wb0 + vb[1] * wb1 + vb[2] * wb2);
      nsum += aa + ab + ba + bb - 2.0f;
    }
    p[4] = nsum;
  }
  const int slot[5] = {0, 1, 2, 3, 4};
  block_accum<5>(p, acc, slot);
}

__global__ __launch_bounds__(BLOCK) void point_kernel(
    const float* __restrict__ pred,   // [M]
    const float* __restrict__ grad,   // [M,3]
    float* __restrict__ acc, int M) {
  int i = blockIdx.x * blockDim.x + threadIdx.x;
  float p[2] = {0.f, 0.f};
  if (i < M) {
    p[0] = __expf(-100.0f * fabsf(pred[i]));
    float gx = grad[3 * i], gy = grad[3 * i + 1], gz = grad[3 * i + 2];
    p[1] = fabsf(sqrtf(gx * gx + gy * gy + gz * gz) - 1.0f);
  }
  const int slot[2] = {5, 1};
  block_accum<2>(p, acc, slot);
}

__global__ void finalize_kernel(const float* __restrict__ acc, float* __restrict__ out,
                                int N, int M) {
  if (threadIdx.x == 0 && blockIdx.x == 0) {
    float sdf = acc[0] / (float)N;
    float eik = acc[1] / (float)(N + M);
    float morse = 0.5f * acc[2] / (3.0f * (float)N);
    float th = 0.5f * acc[3] / (3.0f * (float)N);
    float nb = acc[4] / ((float)N * (float)KVAL);
    float inter = acc[5] / (float)M;
    float loss = 7000.0f * sdf + 600.0f * inter + 50.0f * eik + 3.0f * morse +
                 10.0f * th + 30.0f * nb;
    out[0] = loss; out[1] = sdf; out[2] = inter; out[3] = eik;
    out[4] = morse; out[5] = th; out[6] = nb;
  }
}

extern "C" void kernel_launch(void* const* d_in, const int* in_sizes, int n_in,
                              void* d_out, int out_size, void* d_ws, size_t ws_size,
                              hipStream_t stream) {
  const float* mp    = (const float*)d_in[0];
  const float* npred = (const float*)d_in[1];
  const float* grad  = (const float*)d_in[2];
  const float* ngrad = (const float*)d_in[3];
  const float* H     = (const float*)d_in[4];
  const float* ngt   = (const float*)d_in[5];
  const float* theta = (const float*)d_in[6];
  const float* u     = (const float*)d_in[7];
  const float* v     = (const float*)d_in[8];
  const float* rot   = (const float*)d_in[9];
  const int*   nbr   = (const int*)d_in[10];
  float* acc = (float*)d_ws;
  float* out = (float*)d_out;

  int N = in_sizes[0];
  int M = in_sizes[1];

  hipMemsetAsync(acc, 0, 6 * sizeof(float), stream);
  vertex_kernel<<<(N + BLOCK - 1) / BLOCK, BLOCK, 0, stream>>>(
      mp, grad, H, ngt, theta, u, v, rot, nbr, acc, N);
  point_kernel<<<(M + BLOCK - 1) / BLOCK, BLOCK, 0, stream>>>(npred, ngrad, acc, M);
  finalize_kernel<<<1, 64, 0, stream>>>(acc, out, N, M);
}

// Round 2
// 210.940 us; speedup vs baseline: 1.0720x; 1.0720x over previous
//
#include <hip/hip_runtime.h>
#include <math.h>

// acc layout in d_ws (floats):
// [0]=sdf_sum [1]=eik_sum(M+N) [2]=morse_sum [3]=h_sum [4]=neigh_sum [5]=inter_sum
// d_ws + 256: packed cross-field, N x 16B (8 x f16: va.xyz, vb.xyz, pad, pad)
static constexpr int BLOCK = 256;
static constexpr int WAVES = BLOCK / 64;
static constexpr int KVAL = 4;

union VV { uint4 u4; _Float16 h[8]; };

__device__ __forceinline__ void norm3(float x, float y, float z,
                                      float& ox, float& oy, float& oz) {
  float inv = 1.0f / (sqrtf(x * x + y * y + z * z) + 1e-12f);
  ox = x * inv; oy = y * inv; oz = z * inv;
}

__device__ __forceinline__ void crossfield(const float* __restrict__ u,
                                           const float* __restrict__ v,
                                           const float* __restrict__ theta,
                                           int n, float va[3], float vb[3]) {
  float s, c;
  __sincosf(theta[n], &s, &c);
  float ux = u[3 * n], uy = u[3 * n + 1], uz = u[3 * n + 2];
  float vx = v[3 * n], vy = v[3 * n + 1], vz = v[3 * n + 2];
  norm3(ux * c + vx * s, uy * c + vy * s, uz * c + vz * s, va[0], va[1], va[2]);
  norm3(vx * c - ux * s, vy * c - uy * s, vz * c - uz * s, vb[0], vb[1], vb[2]);
}

template <int NV>
__device__ __forceinline__ void block_accum(float (&p)[NV], float* __restrict__ acc,
                                            const int (&slot)[NV]) {
#pragma unroll
  for (int off = 32; off > 0; off >>= 1)
#pragma unroll
    for (int q = 0; q < NV; ++q) p[q] += __shfl_down(p[q], off, 64);
  __shared__ float sm[WAVES][NV];
  int wave = threadIdx.x >> 6, lane = threadIdx.x & 63;
  if (lane == 0)
#pragma unroll
    for (int q = 0; q < NV; ++q) sm[wave][q] = p[q];
  __syncthreads();
  if (threadIdx.x == 0) {
#pragma unroll
    for (int q = 0; q < NV; ++q) {
      float t = 0.f;
#pragma unroll
      for (int w = 0; w < WAVES; ++w) t += sm[w][q];
      atomicAdd(&acc[slot[q]], t);
    }
  }
}

// ---------------- pass 1: materialize normalized cross-field as f16x8 -------
__global__ __launch_bounds__(BLOCK) void crossfield_kernel(
    const float* __restrict__ theta, const float* __restrict__ u,
    const float* __restrict__ v, uint4* __restrict__ vavb, int N) {
  int n = blockIdx.x * blockDim.x + threadIdx.x;
  if (n >= N) return;
  float va[3], vb[3];
  crossfield(u, v, theta, n, va, vb);
  VV w;
  w.h[0] = (_Float16)va[0]; w.h[1] = (_Float16)va[1]; w.h[2] = (_Float16)va[2];
  w.h[3] = (_Float16)vb[0]; w.h[4] = (_Float16)vb[1]; w.h[5] = (_Float16)vb[2];
  w.h[6] = (_Float16)0.f;   w.h[7] = (_Float16)0.f;
  vavb[n] = w.u4;
}

// ---------------- pass 2: all vertex terms, 16B gather per neighbor ---------
__global__ __launch_bounds__(BLOCK) void vertex_fast_kernel(
    const float* __restrict__ mp,       // [N]
    const float* __restrict__ grad,     // [N,3]
    const float* __restrict__ H,        // [N,9]
    const float* __restrict__ ngt,      // [N,3]
    const uint4* __restrict__ vavb,     // [N] packed f16x8
    const float* __restrict__ rot,      // [N,K,9]
    const int4* __restrict__ nbr,       // [N] (K=4 ints)
    float* __restrict__ acc, int N) {
  int n = blockIdx.x * blockDim.x + threadIdx.x;
  float p[5] = {0.f, 0.f, 0.f, 0.f, 0.f};
  if (n < N) {
    p[0] = fabsf(mp[n]);
    float gx = grad[3 * n], gy = grad[3 * n + 1], gz = grad[3 * n + 2];
    p[1] = fabsf(sqrtf(gx * gx + gy * gy + gz * gz) - 1.0f);
    float h[9];
#pragma unroll
    for (int i = 0; i < 9; ++i) h[i] = H[9 * (size_t)n + i];
    float n0 = ngt[3 * n], n1 = ngt[3 * n + 1], n2 = ngt[3 * n + 2];
    p[2] = fabsf(n0 * h[0] + n1 * h[3] + n2 * h[6]) +
           fabsf(n0 * h[1] + n1 * h[4] + n2 * h[7]) +
           fabsf(n0 * h[2] + n1 * h[5] + n2 * h[8]);
    // self cross-field (coalesced packed load)
    VV ws; ws.u4 = vavb[n];
    float va[3] = {(float)ws.h[0], (float)ws.h[1], (float)ws.h[2]};
    float vb[3] = {(float)ws.h[3], (float)ws.h[4], (float)ws.h[5]};
    {
      float a0 = va[0] * h[0] + va[1] * h[3] + va[2] * h[6];
      float a1 = va[0] * h[1] + va[1] * h[4] + va[2] * h[7];
      float a2 = va[0] * h[2] + va[1] * h[5] + va[2] * h[8];
      float b0 = vb[0] * h[0] + vb[1] * h[3] + vb[2] * h[6];
      float b1 = vb[0] * h[1] + vb[1] * h[4] + vb[2] * h[7];
      float b2 = vb[0] * h[2] + vb[1] * h[5] + vb[2] * h[8];
      p[3] = fabsf(a1 * va[2] - a2 * va[1]) + fabsf(a2 * va[0] - a0 * va[2]) +
             fabsf(a0 * va[1] - a1 * va[0]) + fabsf(b1 * vb[2] - b2 * vb[1]) +
             fabsf(b2 * vb[0] - b0 * vb[2]) + fabsf(b0 * vb[1] - b1 * vb[0]);
    }
    // neighbor consistency: one 16B gather per neighbor
    int4 jj = nbr[n];
    int js[4] = {jj.x, jj.y, jj.z, jj.w};
    VV wn[4];
#pragma unroll
    for (int k = 0; k < KVAL; ++k) wn[k].u4 = vavb[js[k]];  // independent loads
    float nsum = 0.f;
    const float* R = rot + (size_t)n * (KVAL * 9);
#pragma unroll
    for (int k = 0; k < KVAL; ++k) {
      float vaj[3] = {(float)wn[k].h[0], (float)wn[k].h[1], (float)wn[k].h[2]};
      float vbj[3] = {(float)wn[k].h[3], (float)wn[k].h[4], (float)wn[k].h[5]};
      float r0 = R[9 * k + 0], r1 = R[9 * k + 1], r2 = R[9 * k + 2];
      float r3 = R[9 * k + 3], r4 = R[9 * k + 4], r5 = R[9 * k + 5];
      float r6 = R[9 * k + 6], r7 = R[9 * k + 7], r8 = R[9 * k + 8];
      float wa0 = r0 * vaj[0] + r1 * vaj[1] + r2 * vaj[2];
      float wa1 = r3 * vaj[0] + r4 * vaj[1] + r5 * vaj[2];
      float wa2 = r6 * vaj[0] + r7 * vaj[1] + r8 * vaj[2];
      float wb0 = r0 * vbj[0] + r1 * vbj[1] + r2 * vbj[2];
      float wb1 = r3 * vbj[0] + r4 * vbj[1] + r5 * vbj[2];
      float wb2 = r6 * vbj[0] + r7 * vbj[1] + r8 * vbj[2];
      float aa = fabsf(va[0] * wa0 + va[1] * wa1 + va[2] * wa2);
      float ab = fabsf(va[0] * wb0 + va[1] * wb1 + va[2] * wb2);
      float ba = fabsf(vb[0] * wa0 + vb[1] * wa1 + vb[2] * wa2);
      float bb = fabsf(vb[0] * wb0 + vb[1] * wb1 + vb[2] * wb2);
      nsum += aa + ab + ba + bb - 2.0f;
    }
    p[4] = nsum;
  }
  const int slot[5] = {0, 1, 2, 3, 4};
  block_accum<5>(p, acc, slot);
}

// ---------------- fallback (R1 path) if ws too small ------------------------
__global__ __launch_bounds__(BLOCK) void vertex_kernel(
    const float* __restrict__ mp, const float* __restrict__ grad,
    const float* __restrict__ H, const float* __restrict__ ngt,
    const float* __restrict__ theta, const float* __restrict__ u,
    const float* __restrict__ v, const float* __restrict__ rot,
    const int* __restrict__ nbr, float* __restrict__ acc, int N) {
  int n = blockIdx.x * blockDim.x + threadIdx.x;
  float p[5] = {0.f, 0.f, 0.f, 0.f, 0.f};
  if (n < N) {
    p[0] = fabsf(mp[n]);
    float gx = grad[3 * n], gy = grad[3 * n + 1], gz = grad[3 * n + 2];
    p[1] = fabsf(sqrtf(gx * gx + gy * gy + gz * gz) - 1.0f);
    float h[9];
#pragma unroll
    for (int i = 0; i < 9; ++i) h[i] = H[9 * (size_t)n + i];
    float n0 = ngt[3 * n], n1 = ngt[3 * n + 1], n2 = ngt[3 * n + 2];
    p[2] = fabsf(n0 * h[0] + n1 * h[3] + n2 * h[6]) +
           fabsf(n0 * h[1] + n1 * h[4] + n2 * h[7]) +
           fabsf(n0 * h[2] + n1 * h[5] + n2 * h[8]);
    float va[3], vb[3];
    crossfield(u, v, theta, n, va, vb);
    {
      float a0 = va[0] * h[0] + va[1] * h[3] + va[2] * h[6];
      float a1 = va[0] * h[1] + va[1] * h[4] + va[2] * h[7];
      float a2 = va[0] * h[2] + va[1] * h[5] + va[2] * h[8];
      float b0 = vb[0] * h[0] + vb[1] * h[3] + vb[2] * h[6];
      float b1 = vb[0] * h[1] + vb[1] * h[4] + vb[2] * h[7];
      float b2 = vb[0] * h[2] + vb[1] * h[5] + vb[2] * h[8];
      p[3] = fabsf(a1 * va[2] - a2 * va[1]) + fabsf(a2 * va[0] - a0 * va[2]) +
             fabsf(a0 * va[1] - a1 * va[0]) + fabsf(b1 * vb[2] - b2 * vb[1]) +
             fabsf(b2 * vb[0] - b0 * vb[2]) + fabsf(b0 * vb[1] - b1 * vb[0]);
    }
    float nsum = 0.f;
    const float* R = rot + (size_t)n * (KVAL * 9);
#pragma unroll
    for (int k = 0; k < KVAL; ++k) {
      int j = nbr[KVAL * (size_t)n + k];
      float vaj[3], vbj[3];
      crossfield(u, v, theta, j, vaj, vbj);
      float r0 = R[9 * k + 0], r1 = R[9 * k + 1], r2 = R[9 * k + 2];
      float r3 = R[9 * k + 3], r4 = R[9 * k + 4], r5 = R[9 * k + 5];
      float r6 = R[9 * k + 6], r7 = R[9 * k + 7], r8 = R[9 * k + 8];
      float wa0 = r0 * vaj[0] + r1 * vaj[1] + r2 * vaj[2];
      float wa1 = r3 * vaj[0] + r4 * vaj[1] + r5 * vaj[2];
      float wa2 = r6 * vaj[0] + r7 * vaj[1] + r8 * vaj[2];
      float wb0 = r0 * vbj[0] + r1 * vbj[1] + r2 * vbj[2];
      float wb1 = r3 * vbj[0] + r4 * vbj[1] + r5 * vbj[2];
      float wb2 = r6 * vbj[0] + r7 * vbj[1] + r8 * vbj[2];
      nsum += fabsf(va[0] * wa0 + va[1] * wa1 + va[2] * wa2) +
              fabsf(va[0] * wb0 + va[1] * wb1 + va[2] * wb2) +
              fabsf(vb[0] * wa0 + vb[1] * wa1 + vb[2] * wa2) +
              fabsf(vb[0] * wb0 + vb[1] * wb1 + vb[2] * wb2) - 2.0f;
    }
    p[4] = nsum;
  }
  const int slot[5] = {0, 1, 2, 3, 4};
  block_accum<5>(p, acc, slot);
}

__global__ __launch_bounds__(BLOCK) void point_kernel(
    const float* __restrict__ pred, const float* __restrict__ grad,
    float* __restrict__ acc, int M) {
  int i = blockIdx.x * blockDim.x + threadIdx.x;
  float p[2] = {0.f, 0.f};
  if (i < M) {
    p[0] = __expf(-100.0f * fabsf(pred[i]));
    float gx = grad[3 * i], gy = grad[3 * i + 1], gz = grad[3 * i + 2];
    p[1] = fabsf(sqrtf(gx * gx + gy * gy + gz * gz) - 1.0f);
  }
  const int slot[2] = {5, 1};
  block_accum<2>(p, acc, slot);
}

__global__ void finalize_kernel(const float* __restrict__ acc, float* __restrict__ out,
                                int N, int M) {
  if (threadIdx.x == 0 && blockIdx.x == 0) {
    float sdf = acc[0] / (float)N;
    float eik = acc[1] / (float)(N + M);
    float morse = 0.5f * acc[2] / (3.0f * (float)N);
    float th = 0.5f * acc[3] / (3.0f * (float)N);
    float nb = acc[4] / ((float)N * (float)KVAL);
    float inter = acc[5] / (float)M;
    float loss = 7000.0f * sdf + 600.0f * inter + 50.0f * eik + 3.0f * morse +
                 10.0f * th + 30.0f * nb;
    out[0] = loss; out[1] = sdf; out[2] = inter; out[3] = eik;
    out[4] = morse; out[5] = th; out[6] = nb;
  }
}

extern "C" void kernel_launch(void* const* d_in, const int* in_sizes, int n_in,
                              void* d_out, int out_size, void* d_ws, size_t ws_size,
                              hipStream_t stream) {
  const float* mp    = (const float*)d_in[0];
  const float* npred = (const float*)d_in[1];
  const float* grad  = (const float*)d_in[2];
  const float* ngrad = (const float*)d_in[3];
  const float* H     = (const float*)d_in[4];
  const float* ngt   = (const float*)d_in[5];
  const float* theta = (const float*)d_in[6];
  const float* u     = (const float*)d_in[7];
  const float* v     = (const float*)d_in[8];
  const float* rot   = (const float*)d_in[9];
  const int*   nbr   = (const int*)d_in[10];
  float* acc = (float*)d_ws;
  float* out = (float*)d_out;

  int N = in_sizes[0];
  int M = in_sizes[1];
  int gN = (N + BLOCK - 1) / BLOCK;

  hipMemsetAsync(acc, 0, 6 * sizeof(float), stream);

  size_t need = 256 + (size_t)N * 16;
  if (ws_size >= need) {
    uint4* vavb = (uint4*)((char*)d_ws + 256);
    crossfield_kernel<<<gN, BLOCK, 0, stream>>>(theta, u, v, vavb, N);
    vertex_fast_kernel<<<gN, BLOCK, 0, stream>>>(
        mp, grad, H, ngt, vavb, rot, (const int4*)nbr, acc, N);
  } else {
    vertex_kernel<<<gN, BLOCK, 0, stream>>>(
        mp, grad, H, ngt, theta, u, v, rot, nbr, acc, N);
  }
  point_kernel<<<(M + BLOCK - 1) / BLOCK, BLOCK, 0, stream>>>(npred, ngrad, acc, M);
  finalize_kernel<<<1, 64, 0, stream>>>(acc, out, N, M);
}

// Round 3
// 163.703 us; speedup vs baseline: 1.3814x; 1.2886x over previous
//
#include <hip/hip_runtime.h>
#include <math.h>

// acc layout in d_ws (floats):
// [0]=sdf_sum [1]=eik_sum(M+N) [2]=morse_sum [3]=h_sum [4]=neigh_sum [5]=inter_sum
// d_ws + 256: packed cross-field, N x 16B (8 x f16: va.xyz, vb.xyz, pad, pad)
static constexpr int BLOCK = 256;
static constexpr int WAVES = BLOCK / 64;
static constexpr int KVAL = 4;

typedef float f4 __attribute__((ext_vector_type(4)));
union VV { uint4 u4; _Float16 h[8]; };

__device__ __forceinline__ float ntl(const float* p) {
  return __builtin_nontemporal_load(p);
}
__device__ __forceinline__ f4 ntl4(const f4* p) {
  return __builtin_nontemporal_load(p);
}
__device__ __forceinline__ int nti(const int* p) {
  return __builtin_nontemporal_load(p);
}

__device__ __forceinline__ void norm3(float x, float y, float z,
                                      float& ox, float& oy, float& oz) {
  float inv = 1.0f / (sqrtf(x * x + y * y + z * z) + 1e-12f);
  ox = x * inv; oy = y * inv; oz = z * inv;
}

__device__ __forceinline__ void crossfield(const float* __restrict__ u,
                                           const float* __restrict__ v,
                                           const float* __restrict__ theta,
                                           int n, float va[3], float vb[3]) {
  float s, c;
  __sincosf(theta[n], &s, &c);
  float ux = u[3 * n], uy = u[3 * n + 1], uz = u[3 * n + 2];
  float vx = v[3 * n], vy = v[3 * n + 1], vz = v[3 * n + 2];
  norm3(ux * c + vx * s, uy * c + vy * s, uz * c + vz * s, va[0], va[1], va[2]);
  norm3(vx * c - ux * s, vy * c - uy * s, vz * c - uz * s, vb[0], vb[1], vb[2]);
}

template <int NV>
__device__ __forceinline__ void block_accum(float (&p)[NV], float* __restrict__ acc,
                                            const int (&slot)[NV]) {
#pragma unroll
  for (int off = 32; off > 0; off >>= 1)
#pragma unroll
    for (int q = 0; q < NV; ++q) p[q] += __shfl_down(p[q], off, 64);
  __shared__ float sm[WAVES][NV];
  int wave = threadIdx.x >> 6, lane = threadIdx.x & 63;
  if (lane == 0)
#pragma unroll
    for (int q = 0; q < NV; ++q) sm[wave][q] = p[q];
  __syncthreads();
  if (threadIdx.x == 0) {
#pragma unroll
    for (int q = 0; q < NV; ++q) {
      float t = 0.f;
#pragma unroll
      for (int w = 0; w < WAVES; ++w) t += sm[w][q];
      atomicAdd(&acc[slot[q]], t);
    }
  }
}

// ---- pass 1: cross-field materialization (f16x8) FUSED with point terms ----
__global__ __launch_bounds__(BLOCK) void pass1_kernel(
    const float* __restrict__ theta, const float* __restrict__ u,
    const float* __restrict__ v, uint4* __restrict__ vavb, int N,
    const float* __restrict__ pred, const float* __restrict__ pgrad,
    float* __restrict__ acc, int M) {
  int i = blockIdx.x * blockDim.x + threadIdx.x;
  float p[2] = {0.f, 0.f};
  if (i < M) {
    p[0] = __expf(-100.0f * fabsf(ntl(pred + i)));
    float gx = ntl(pgrad + 3 * i), gy = ntl(pgrad + 3 * i + 1),
          gz = ntl(pgrad + 3 * i + 2);
    p[1] = fabsf(sqrtf(gx * gx + gy * gy + gz * gz) - 1.0f);
  }
  if (i < N) {
    float va[3], vb[3];
    crossfield(u, v, theta, i, va, vb);
    VV w;
    w.h[0] = (_Float16)va[0]; w.h[1] = (_Float16)va[1]; w.h[2] = (_Float16)va[2];
    w.h[3] = (_Float16)vb[0]; w.h[4] = (_Float16)vb[1]; w.h[5] = (_Float16)vb[2];
    w.h[6] = (_Float16)0.f;   w.h[7] = (_Float16)0.f;
    vavb[i] = w.u4;
  }
  const int slot[2] = {5, 1};
  block_accum<2>(p, acc, slot);
}

// ---- pass 2: vertex terms, 2 vertices/thread, nt streams, early gathers ----
__device__ __forceinline__ void vertex_terms(
    int n, bool act, const float* __restrict__ mp, const float* __restrict__ grad,
    const float* __restrict__ H, const float* __restrict__ ngt,
    const uint4* __restrict__ vavb, const float* __restrict__ rot,
    const VV (&wn)[4], float (&p)[5]) {
  if (!act) return;
  p[0] += fabsf(ntl(mp + n));
  float gx = ntl(grad + 3 * n), gy = ntl(grad + 3 * n + 1), gz = ntl(grad + 3 * n + 2);
  p[1] += fabsf(sqrtf(gx * gx + gy * gy + gz * gz) - 1.0f);
  float h[9];
#pragma unroll
  for (int i = 0; i < 9; ++i) h[i] = ntl(H + 9 * (size_t)n + i);
  float n0 = ntl(ngt + 3 * n), n1 = ntl(ngt + 3 * n + 1), n2 = ntl(ngt + 3 * n + 2);
  p[2] += fabsf(n0 * h[0] + n1 * h[3] + n2 * h[6]) +
          fabsf(n0 * h[1] + n1 * h[4] + n2 * h[7]) +
          fabsf(n0 * h[2] + n1 * h[5] + n2 * h[8]);
  VV ws; ws.u4 = vavb[n];
  float va[3] = {(float)ws.h[0], (float)ws.h[1], (float)ws.h[2]};
  float vb[3] = {(float)ws.h[3], (float)ws.h[4], (float)ws.h[5]};
  {
    float a0 = va[0] * h[0] + va[1] * h[3] + va[2] * h[6];
    float a1 = va[0] * h[1] + va[1] * h[4] + va[2] * h[7];
    float a2 = va[0] * h[2] + va[1] * h[5] + va[2] * h[8];
    float b0 = vb[0] * h[0] + vb[1] * h[3] + vb[2] * h[6];
    float b1 = vb[0] * h[1] + vb[1] * h[4] + vb[2] * h[7];
    float b2 = vb[0] * h[2] + vb[1] * h[5] + vb[2] * h[8];
    p[3] += fabsf(a1 * va[2] - a2 * va[1]) + fabsf(a2 * va[0] - a0 * va[2]) +
            fabsf(a0 * va[1] - a1 * va[0]) + fabsf(b1 * vb[2] - b2 * vb[1]) +
            fabsf(b2 * vb[0] - b0 * vb[2]) + fabsf(b0 * vb[1] - b1 * vb[0]);
  }
  // rot: 16B-aligned (144B/vertex) -> 9 nontemporal float4 loads
  const f4* rv = (const f4*)(rot + (size_t)n * 36);
  float r[36];
#pragma unroll
  for (int q = 0; q < 9; ++q) {
    f4 t = ntl4(rv + q);
    r[4 * q] = t.x; r[4 * q + 1] = t.y; r[4 * q + 2] = t.z; r[4 * q + 3] = t.w;
  }
  float nsum = 0.f;
#pragma unroll
  for (int k = 0; k < KVAL; ++k) {
    float vaj[3] = {(float)wn[k].h[0], (float)wn[k].h[1], (float)wn[k].h[2]};
    float vbj[3] = {(float)wn[k].h[3], (float)wn[k].h[4], (float)wn[k].h[5]};
    const float* R = r + 9 * k;
    float wa0 = R[0] * vaj[0] + R[1] * vaj[1] + R[2] * vaj[2];
    float wa1 = R[3] * vaj[0] + R[4] * vaj[1] + R[5] * vaj[2];
    float wa2 = R[6] * vaj[0] + R[7] * vaj[1] + R[8] * vaj[2];
    float wb0 = R[0] * vbj[0] + R[1] * vbj[1] + R[2] * vbj[2];
    float wb1 = R[3] * vbj[0] + R[4] * vbj[1] + R[5] * vbj[2];
    float wb2 = R[6] * vbj[0] + R[7] * vbj[1] + R[8] * vbj[2];
    nsum += fabsf(va[0] * wa0 + va[1] * wa1 + va[2] * wa2) +
            fabsf(va[0] * wb0 + va[1] * wb1 + va[2] * wb2) +
            fabsf(vb[0] * wa0 + vb[1] * wa1 + vb[2] * wa2) +
            fabsf(vb[0] * wb0 + vb[1] * wb1 + vb[2] * wb2) - 2.0f;
  }
  p[4] += nsum;
}

__global__ __launch_bounds__(BLOCK) void vertex2_kernel(
    const float* __restrict__ mp, const float* __restrict__ grad,
    const float* __restrict__ H, const float* __restrict__ ngt,
    const uint4* __restrict__ vavb, const float* __restrict__ rot,
    const int* __restrict__ nbr, float* __restrict__ acc, int N) {
  int n0 = blockIdx.x * (BLOCK * 2) + threadIdx.x;
  int n1 = n0 + BLOCK;
  bool a0 = n0 < N, a1 = n1 < N;
  // issue neighbor index loads + all 8 gathers first (max MLP)
  int j0[4] = {0, 0, 0, 0}, j1[4] = {0, 0, 0, 0};
  if (a0) {
#pragma unroll
    for (int k = 0; k < KVAL; ++k) j0[k] = nti(nbr + 4 * (size_t)n0 + k);
  }
  if (a1) {
#pragma unroll
    for (int k = 0; k < KVAL; ++k) j1[k] = nti(nbr + 4 * (size_t)n1 + k);
  }
  VV g0[4], g1[4];
#pragma unroll
  for (int k = 0; k < KVAL; ++k) g0[k].u4 = vavb[j0[k]];
#pragma unroll
  for (int k = 0; k < KVAL; ++k) g1[k].u4 = vavb[j1[k]];

  float p[5] = {0.f, 0.f, 0.f, 0.f, 0.f};
  vertex_terms(n0, a0, mp, grad, H, ngt, vavb, rot, g0, p);
  vertex_terms(n1, a1, mp, grad, H, ngt, vavb, rot, g1, p);
  const int slot[5] = {0, 1, 2, 3, 4};
  block_accum<5>(p, acc, slot);
}

// ---------------- fallback (recompute) if ws too small ----------------------
__global__ __launch_bounds__(BLOCK) void vertex_kernel(
    const float* __restrict__ mp, const float* __restrict__ grad,
    const float* __restrict__ H, const float* __restrict__ ngt,
    const float* __restrict__ theta, const float* __restrict__ u,
    const float* __restrict__ v, const float* __restrict__ rot,
    const int* __restrict__ nbr, float* __restrict__ acc, int N) {
  int n = blockIdx.x * blockDim.x + threadIdx.x;
  float p[5] = {0.f, 0.f, 0.f, 0.f, 0.f};
  if (n < N) {
    p[0] = fabsf(mp[n]);
    float gx = grad[3 * n], gy = grad[3 * n + 1], gz = grad[3 * n + 2];
    p[1] = fabsf(sqrtf(gx * gx + gy * gy + gz * gz) - 1.0f);
    float h[9];
#pragma unroll
    for (int i = 0; i < 9; ++i) h[i] = H[9 * (size_t)n + i];
    float n0 = ngt[3 * n], n1 = ngt[3 * n + 1], n2 = ngt[3 * n + 2];
    p[2] = fabsf(n0 * h[0] + n1 * h[3] + n2 * h[6]) +
           fabsf(n0 * h[1] + n1 * h[4] + n2 * h[7]) +
           fabsf(n0 * h[2] + n1 * h[5] + n2 * h[8]);
    float va[3], vb[3];
    crossfield(u, v, theta, n, va, vb);
    {
      float a0 = va[0] * h[0] + va[1] * h[3] + va[2] * h[6];
      float a1 = va[0] * h[1] + va[1] * h[4] + va[2] * h[7];
      float a2 = va[0] * h[2] + va[1] * h[5] + va[2] * h[8];
      float b0 = vb[0] * h[0] + vb[1] * h[3] + vb[2] * h[6];
      float b1 = vb[0] * h[1] + vb[1] * h[4] + vb[2] * h[7];
      float b2 = vb[0] * h[2] + vb[1] * h[5] + vb[2] * h[8];
      p[3] = fabsf(a1 * va[2] - a2 * va[1]) + fabsf(a2 * va[0] - a0 * va[2]) +
             fabsf(a0 * va[1] - a1 * va[0]) + fabsf(b1 * vb[2] - b2 * vb[1]) +
             fabsf(b2 * vb[0] - b0 * vb[2]) + fabsf(b0 * vb[1] - b1 * vb[0]);
    }
    float nsum = 0.f;
    const float* R = rot + (size_t)n * (KVAL * 9);
#pragma unroll
    for (int k = 0; k < KVAL; ++k) {
      int j = nbr[KVAL * (size_t)n + k];
      float vaj[3], vbj[3];
      crossfield(u, v, theta, j, vaj, vbj);
      float r0 = R[9 * k + 0], r1 = R[9 * k + 1], r2 = R[9 * k + 2];
      float r3 = R[9 * k + 3], r4 = R[9 * k + 4], r5 = R[9 * k + 5];
      float r6 = R[9 * k + 6], r7 = R[9 * k + 7], r8 = R[9 * k + 8];
      float wa0 = r0 * vaj[0] + r1 * vaj[1] + r2 * vaj[2];
      float wa1 = r3 * vaj[0] + r4 * vaj[1] + r5 * vaj[2];
      float wa2 = r6 * vaj[0] + r7 * vaj[1] + r8 * vaj[2];
      float wb0 = r0 * vbj[0] + r1 * vbj[1] + r2 * vbj[2];
      float wb1 = r3 * vbj[0] + r4 * vbj[1] + r5 * vbj[2];
      float wb2 = r6 * vbj[0] + r7 * vbj[1] + r8 * vbj[2];
      nsum += fabsf(va[0] * wa0 + va[1] * wa1 + va[2] * wa2) +
              fabsf(va[0] * wb0 + va[1] * wb1 + va[2] * wb2) +
              fabsf(vb[0] * wa0 + vb[1] * wa1 + vb[2] * wa2) +
              fabsf(vb[0] * wb0 + vb[1] * wb1 + vb[2] * wb2) - 2.0f;
    }
    p[4] = nsum;
  }
  const int slot[5] = {0, 1, 2, 3, 4};
  block_accum<5>(p, acc, slot);
}

__global__ __launch_bounds__(BLOCK) void point_kernel(
    const float* __restrict__ pred, const float* __restrict__ grad,
    float* __restrict__ acc, int M) {
  int i = blockIdx.x * blockDim.x + threadIdx.x;
  float p[2] = {0.f, 0.f};
  if (i < M) {
    p[0] = __expf(-100.0f * fabsf(pred[i]));
    float gx = grad[3 * i], gy = grad[3 * i + 1], gz = grad[3 * i + 2];
    p[1] = fabsf(sqrtf(gx * gx + gy * gy + gz * gz) - 1.0f);
  }
  const int slot[2] = {5, 1};
  block_accum<2>(p, acc, slot);
}

__global__ void finalize_kernel(const float* __restrict__ acc, float* __restrict__ out,
                                int N, int M) {
  if (threadIdx.x == 0 && blockIdx.x == 0) {
    float sdf = acc[0] / (float)N;
    float eik = acc[1] / (float)(N + M);
    float morse = 0.5f * acc[2] / (3.0f * (float)N);
    float th = 0.5f * acc[3] / (3.0f * (float)N);
    float nb = acc[4] / ((float)N * (float)KVAL);
    float inter = acc[5] / (float)M;
    float loss = 7000.0f * sdf + 600.0f * inter + 50.0f * eik + 3.0f * morse +
                 10.0f * th + 30.0f * nb;
    out[0] = loss; out[1] = sdf; out[2] = inter; out[3] = eik;
    out[4] = morse; out[5] = th; out[6] = nb;
  }
}

extern "C" void kernel_launch(void* const* d_in, const int* in_sizes, int n_in,
                              void* d_out, int out_size, void* d_ws, size_t ws_size,
                              hipStream_t stream) {
  const float* mp    = (const float*)d_in[0];
  const float* npred = (const float*)d_in[1];
  const float* grad  = (const float*)d_in[2];
  const float* ngrad = (const float*)d_in[3];
  const float* H     = (const float*)d_in[4];
  const float* ngt   = (const float*)d_in[5];
  const float* theta = (const float*)d_in[6];
  const float* u     = (const float*)d_in[7];
  const float* v     = (const float*)d_in[8];
  const float* rot   = (const float*)d_in[9];
  const int*   nbr   = (const int*)d_in[10];
  float* acc = (float*)d_ws;
  float* out = (float*)d_out;

  int N = in_sizes[0];
  int M = in_sizes[1];

  hipMemsetAsync(acc, 0, 6 * sizeof(float), stream);

  size_t need = 256 + (size_t)N * 16;
  if (ws_size >= need) {
    uint4* vavb = (uint4*)((char*)d_ws + 256);
    int nm = (N > M) ? N : M;
    pass1_kernel<<<(nm + BLOCK - 1) / BLOCK, BLOCK, 0, stream>>>(
        theta, u, v, vavb, N, npred, ngrad, acc, M);
    vertex2_kernel<<<(N + 2 * BLOCK - 1) / (2 * BLOCK), BLOCK, 0, stream>>>(
        mp, grad, H, ngt, vavb, rot, nbr, acc, N);
  } else {
    vertex_kernel<<<(N + BLOCK - 1) / BLOCK, BLOCK, 0, stream>>>(
        mp, grad, H, ngt, theta, u, v, rot, nbr, acc, N);
    point_kernel<<<(M + BLOCK - 1) / BLOCK, BLOCK, 0, stream>>>(npred, ngrad, acc, M);
  }
  finalize_kernel<<<1, 64, 0, stream>>>(acc, out, N, M);
}